// Round 2
// baseline (394.415 us; speedup 1.0000x reference)
//
#include <hip/hip_runtime.h>

#define CIN 512
#define COUT 512
#define HH 64
#define WW 64
#define BB 8
#define KTOT 4608   // 512*9

#define XPD 66      // padded spatial dim: index = coord+1, coord in -1..64
#define NSL 66      // LDS col-slices per row (icol 0..65)

typedef __attribute__((ext_vector_type(8))) short short8;
typedef __attribute__((ext_vector_type(4))) float f32x4;

__device__ inline unsigned short f2bf(float f) {
    unsigned int u = __float_as_uint(f);
    u += 0x7FFFu + ((u >> 16) & 1u);   // round-to-nearest-even
    return (unsigned short)(u >> 16);
}

__device__ inline void gll16(const void* g, void* l) {
    __builtin_amdgcn_global_load_lds(
        (const __attribute__((address_space(1))) unsigned int*)g,
        (__attribute__((address_space(3))) unsigned int*)l, 16, 0, 0);
}

// ---------------- Phase -1: zero-fill padded XTP ----------------
__global__ __launch_bounds__(256) void zerox_kernel(short8* __restrict__ p, int n8) {
    int i = blockIdx.x * 256 + threadIdx.x;
    const int stride = gridDim.x * 256;
    const short8 z = (short8){0, 0, 0, 0, 0, 0, 0, 0};
    for (; i < n8; i += stride) p[i] = z;
}

// ---------------- Phase 0: x [b][i][y][x] fp32 -> XTP [b][y+1][x+1][i] bf16 ----------------
__global__ __launch_bounds__(256) void xpose_kernel(const float* __restrict__ x,
                                                    unsigned short* __restrict__ xtp) {
    __shared__ float tile[32 * 65];
    const int ic = blockIdx.x;   // 16 groups of 32 channels
    const int y  = blockIdx.y;
    const int b  = blockIdx.z;
    const int t  = threadIdx.x;
#pragma unroll
    for (int it = 0; it < 8; ++it) {
        int e = it * 256 + t;
        int ii = e >> 6, xx = e & 63;
        tile[ii * 65 + xx] = x[(((size_t)(b * CIN + ic * 32 + ii) * HH + y) << 6) + xx];
    }
    __syncthreads();
#pragma unroll
    for (int it = 0; it < 8; ++it) {
        int g = it * 256 + t;
        int xx = g >> 5, ii = g & 31;
        xtp[((size_t)(b * XPD + y + 1) * XPD + xx + 1) * 512 + ic * 32 + ii] =
            f2bf(tile[ii * 65 + xx]);
    }
}

// ---------------- Phase 1: modulated weights, MFMA-fragment-packed ----------------
// Wp flat: ((((b*9+tap)*32 + g)*16 + c)*64 + lane)*8 + e
//   lane = l4*16+l15: holds W[o=g*16+l15][i=c*32+l4*8+e]
__global__ __launch_bounds__(256) void modw_kernel(const float* __restrict__ weight,
                                                   const float* __restrict__ style,
                                                   unsigned short* __restrict__ wp) {
    __shared__ float q[KTOT];
    __shared__ float redbuf[4];
    __shared__ float s_scale;
    const int o = blockIdx.x;
    const int b = blockIdx.y;
    const int t = threadIdx.x;
    const float* wrow = weight + (size_t)o * KTOT;   // e = i*9+tap
    const float* st   = style + b * CIN;

    float ss = 0.f;
#pragma unroll
    for (int it = 0; it < 18; ++it) {
        int e = it * 256 + t;
        int i = e / 9;
        float v = wrow[e] * (st[i] + 1.0f);
        q[e] = v;
        ss += v * v;
    }
#pragma unroll
    for (int off = 32; off > 0; off >>= 1) ss += __shfl_down(ss, off, 64);
    int wid = t >> 6;
    if ((t & 63) == 0) redbuf[wid] = ss;
    __syncthreads();
    if (t == 0) {
        float S = redbuf[0] + redbuf[1] + redbuf[2] + redbuf[3];
        const float c = 1.0f / sqrtf((float)KTOT);
        s_scale = c * rsqrtf(S * (1.0f / (float)KTOT) + 1e-8f);
    }
    __syncthreads();
    const float scale = s_scale;
    const int g = o >> 4, l15 = o & 15;
    for (int m = t; m < 576; m += 256) {   // (tap, c, l4)
        int tap = m / 64;
        int rem = m & 63;
        int c   = rem >> 2;
        int l4  = rem & 3;
        short8 v;
#pragma unroll
        for (int e = 0; e < 8; ++e)
            v[e] = (short)f2bf(q[(c * 32 + l4 * 8 + e) * 9 + tap] * scale);
        size_t dst = ((((size_t)(b * 9 + tap) * 32 + g) * 16 + c) * 64 + l4 * 16 + l15) * 8;
        *(short8*)(wp + dst) = v;
    }
}

// ---------------- Phase 2: implicit-GEMM conv ----------------
// block: 128 o x (4 rows x 64 cols). 4 waves: wave = (rp = wid>>1, oh = wid&1),
// each wave 64 o x 128 px -> acc[4][8].
// LDS X tile: [6 input rows][66 col-slices][128B ch-chunk], XOR-swizzled ch-units.
__global__ __launch_bounds__(256, 2) void conv_kernel(const unsigned short* __restrict__ wp,
                                                      const unsigned short* __restrict__ xtp,
                                                      const float* __restrict__ bias,
                                                      float* __restrict__ out) {
    __shared__ __align__(16) unsigned short xs[6 * NSL * 64];   // 50688 B
    // XCD-aware decode: XCD k runs pairs {k,k+8,k+16,k+24}, all 16 yb's contiguous.
    const int bid = blockIdx.x;
    const int k  = bid & 7;
    const int tq = bid >> 3;            // 0..63
    const int p  = k + 8 * (tq >> 4);   // (b,ob) pair 0..31
    const int yb = tq & 15;
    const int b  = p >> 2, ob = p & 3;

    const int tid  = threadIdx.x;
    const int lane = tid & 63, wid = tid >> 6;
    const int l15 = lane & 15, l4 = lane >> 4;
    const int l8  = lane & 7,  lq = lane >> 3;
    const int oh = wid & 1, rp = wid >> 1;
    const int y0 = yb * 4;
    const int g0 = ob * 8 + oh * 4;

    const unsigned short* wfrag = wp + (size_t)b * (9 * 32 * 16 * 64 * 8);

    f32x4 acc[4][8];
#pragma unroll
    for (int mi = 0; mi < 4; ++mi)
#pragma unroll
        for (int j = 0; j < 8; ++j) acc[mi][j] = (f32x4){0.f, 0.f, 0.f, 0.f};

#define LOAD_AF(dst, tap, c)                                                              \
    do {                                                                                  \
        _Pragma("unroll") for (int mi = 0; mi < 4; ++mi)                                  \
            dst[mi] = *(const short8*)(wfrag +                                            \
                ((((size_t)(tap) * 32 + g0 + mi) * 16 + (c)) * 64 + lane) * 8);           \
    } while (0)

#define COMPUTE(af, ky, kx, ks)                                                           \
    do {                                                                                  \
        short8 bfr[8];                                                                    \
        _Pragma("unroll") for (int j = 0; j < 8; ++j) {                                   \
            const int irow = rp * 2 + (j >> 2) + (ky);                                    \
            const int icol = (j & 3) * 16 + l15 + (kx);                                   \
            const int unit = ((ks) * 4 + l4) ^ ((l15 + (kx)) & 7);                        \
            bfr[j] = *(const short8*)(xs + (irow * NSL + icol) * 64 + unit * 8);          \
        }                                                                                 \
        _Pragma("unroll") for (int mi = 0; mi < 4; ++mi)                                  \
            _Pragma("unroll") for (int j = 0; j < 8; ++j)                                 \
                acc[mi][j] = __builtin_amdgcn_mfma_f32_16x16x32_bf16(                     \
                    af[mi], bfr[j], acc[mi][j], 0, 0, 0);                                 \
    } while (0)

    short8 afA[4], afB[4];
    LOAD_AF(afA, 0, 0);

#pragma unroll 1
    for (int ic = 0; ic < 8; ++ic) {
        __syncthreads();
        // stage 6 rows x 66 slices of 128B via global_load_lds (pre-swizzled source)
        for (int q = wid; q < 54; q += 4) {
            const int ir  = q / 9;
            const int sub = q - ir * 9;
            const int yin = y0 - 1 + ir;                       // -1..64 -> padded idx +1
            const unsigned short* srow =
                xtp + (size_t)(b * XPD + yin + 1) * XPD * 512;
            if (sub < 8) {
                const int xcol = sub * 8 + lq;                  // x&7 == lq
                gll16(srow + (size_t)xcol * 512 + ic * 64 + (l8 ^ lq) * 8,
                      xs + (ir * NSL + sub * 8) * 64);
            } else if (lane < 16) {
                const int xcol = 64 + lq;                       // lq in {0,1}, x&7 == lq
                gll16(srow + (size_t)xcol * 512 + ic * 64 + (l8 ^ lq) * 8,
                      xs + (ir * NSL + 64) * 64);
            }
        }
        __syncthreads();

        const int c0 = ic * 2, c1 = c0 + 1;
        const int cn = (ic < 7) ? c0 + 2 : 0;
#pragma unroll
        for (int tp = 0; tp < 9; ++tp) {
            const int ky = tp / 3, kx = tp % 3;
            LOAD_AF(afB, tp, c1);
            COMPUTE(afA, ky, kx, 0);
            if (tp < 8) { LOAD_AF(afA, tp + 1, c0); }
            else        { LOAD_AF(afA, 0, cn); }
            COMPUTE(afB, ky, kx, 1);
        }
    }

    // epilogue: D-frag col = l15 (px), row = l4*4 + rr (o)
#pragma unroll
    for (int mi = 0; mi < 4; ++mi) {
        const int obase = ob * 128 + oh * 64 + mi * 16 + l4 * 4;
#pragma unroll
        for (int rr = 0; rr < 4; ++rr) {
            const int o = obase + rr;
            const float bv = bias[o];
#pragma unroll
            for (int j = 0; j < 8; ++j) {
                const int yout = y0 + rp * 2 + (j >> 2);
                out[(((size_t)(b * COUT + o) * HH + yout) << 6) + (j & 3) * 16 + l15] =
                    acc[mi][j][rr] + bv;
            }
        }
    }
#undef LOAD_AF
#undef COMPUTE
}

extern "C" void kernel_launch(void* const* d_in, const int* in_sizes, int n_in,
                              void* d_out, int out_size, void* d_ws, size_t ws_size,
                              hipStream_t stream) {
    const float* x      = (const float*)d_in[0];
    const float* style  = (const float*)d_in[1];
    const float* weight = (const float*)d_in[2];
    const float* bias   = (const float*)d_in[3];
    float* out = (float*)d_out;

    unsigned short* wp  = (unsigned short*)d_ws;            // 8*9*512*512 bf16 = 37.75 MB
    unsigned short* xtp = wp + (size_t)BB * 9 * COUT * CIN; // 8*66*66*512 bf16 = 35.68 MB

    const int n8 = BB * XPD * XPD * CIN / 8;
    zerox_kernel<<<4096, 256, 0, stream>>>((short8*)xtp, n8);
    xpose_kernel<<<dim3(16, HH, BB), 256, 0, stream>>>(x, xtp);
    modw_kernel<<<dim3(COUT, BB), 256, 0, stream>>>(weight, style, wp);
    conv_kernel<<<512, 256, 0, stream>>>(wp, xtp, bias, out);
}

// Round 3
// 367.814 us; speedup vs baseline: 1.0723x; 1.0723x over previous
//
#include <hip/hip_runtime.h>

#define CIN 512
#define COUT 512
#define HH 64
#define WW 64
#define BB 8
#define KTOT 4608   // 512*9

#define XPD 66      // padded spatial dim: index = coord+1, coord in -1..64
#define NSL 66      // LDS col-slices per row (icol 0..65)

typedef __attribute__((ext_vector_type(8))) short short8;
typedef __attribute__((ext_vector_type(4))) float f32x4;

__device__ inline unsigned short f2bf(float f) {
    unsigned int u = __float_as_uint(f);
    u += 0x7FFFu + ((u >> 16) & 1u);   // round-to-nearest-even
    return (unsigned short)(u >> 16);
}

__device__ inline void gll16(const void* g, void* l) {
    __builtin_amdgcn_global_load_lds(
        (const __attribute__((address_space(1))) unsigned int*)g,
        (__attribute__((address_space(3))) unsigned int*)l, 16, 0, 0);
}

// ---------------- Phase -1: zero the halo ring of XTP ----------------
__global__ __launch_bounds__(256) void zring_kernel(unsigned short* __restrict__ xtp) {
    const int e = blockIdx.x * 256 + threadIdx.x;   // 520*256 >= 8*260*64
    if (e >= BB * 260 * 64) return;
    const int unit = e & 63;
    const int sa = e >> 6;           // 0..2079
    const int b = sa / 260;
    const int s = sa - b * 260;
    int yy, xx;
    if (s < 66)       { yy = 0;        xx = s; }
    else if (s < 132) { yy = 65;       xx = s - 66; }
    else if (s < 196) { yy = s - 131;  xx = 0; }     // rows 1..64
    else              { yy = s - 195;  xx = 65; }    // rows 1..64
    *(short8*)(xtp + ((size_t)(b * XPD + yy) * XPD + xx) * 512 + unit * 8) =
        (short8){0, 0, 0, 0, 0, 0, 0, 0};
}

// ------- Phase 0: x [b][i][y][x] fp32 * (1+style[b][i]) -> XTP [b][y+1][x+1][i] bf16 -------
__global__ __launch_bounds__(256) void xpose_kernel(const float* __restrict__ x,
                                                    const float* __restrict__ style,
                                                    unsigned short* __restrict__ xtp) {
    __shared__ float tile[32 * 65];
    __shared__ float sst[32];
    const int ic = blockIdx.x;   // 16 groups of 32 channels
    const int y  = blockIdx.y;
    const int b  = blockIdx.z;
    const int t  = threadIdx.x;
    if (t < 32) sst[t] = style[b * CIN + ic * 32 + t] + 1.0f;
#pragma unroll
    for (int it = 0; it < 8; ++it) {
        int e = it * 256 + t;
        int ii = e >> 6, xx = e & 63;
        tile[ii * 65 + xx] = x[(((size_t)(b * CIN + ic * 32 + ii) * HH + y) << 6) + xx];
    }
    __syncthreads();
#pragma unroll
    for (int it = 0; it < 8; ++it) {
        int g = it * 256 + t;
        int xx = g >> 5, ii = g & 31;
        xtp[((size_t)(b * XPD + y + 1) * XPD + xx + 1) * 512 + ic * 32 + ii] =
            f2bf(tile[ii * 65 + xx] * sst[ii]);
    }
}

// ---------------- Phase 1a: pack w*c into MFMA fragment layout (batch-independent) -------
// Wpk flat: (((tap*32 + g)*16 + c)*64 + lane)*8 + e ; lane = l4*16+l15 holds
//   W[o = g*16+l15][i = c*32 + l4*8 + e]
__global__ __launch_bounds__(256) void wpack_kernel(const float* __restrict__ weight,
                                                    unsigned short* __restrict__ wpk) {
    __shared__ float q[KTOT];
    const int o = blockIdx.x;
    const int t = threadIdx.x;
    const float* wrow = weight + (size_t)o * KTOT;   // e = i*9+tap
    const float cst = 1.0f / sqrtf((float)KTOT);
#pragma unroll
    for (int it = 0; it < 18; ++it) {
        int e = it * 256 + t;
        q[e] = wrow[e] * cst;
    }
    __syncthreads();
    const int g = o >> 4, l15 = o & 15;
    for (int m = t; m < 576; m += 256) {   // (tap, c, l4)
        int tap = m / 64;
        int rem = m & 63;
        int c   = rem >> 2;
        int l4  = rem & 3;
        short8 v;
#pragma unroll
        for (int e = 0; e < 8; ++e)
            v[e] = (short)f2bf(q[(c * 32 + l4 * 8 + e) * 9 + tap]);
        *(short8*)(wpk + ((((size_t)tap * 32 + g) * 16 + c) * 64 + l4 * 16 + l15) * 8) = v;
    }
}

// ---------------- Phase 1b: sigma_inv[b][o] = rsqrt(c^2 * sum_i wsq[o,i]*(1+s)^2 + eps) ----
__global__ __launch_bounds__(256) void sigma_kernel(const float* __restrict__ weight,
                                                    const float* __restrict__ style,
                                                    float* __restrict__ siginv) {
    __shared__ float sred[4][8];
    const int o = blockIdx.x;
    const int t = threadIdx.x;
    const float* wrow = weight + (size_t)o * KTOT;
    float acc[8] = {0.f, 0.f, 0.f, 0.f, 0.f, 0.f, 0.f, 0.f};
#pragma unroll
    for (int ii = 0; ii < 2; ++ii) {
        const int i = t * 2 + ii;
        float wsq = 0.f;
#pragma unroll
        for (int tap = 0; tap < 9; ++tap) {
            float v = wrow[i * 9 + tap];
            wsq += v * v;
        }
#pragma unroll
        for (int b = 0; b < 8; ++b) {
            float s = style[b * CIN + i] + 1.0f;
            acc[b] += wsq * s * s;
        }
    }
#pragma unroll
    for (int b = 0; b < 8; ++b) {
        float v = acc[b];
#pragma unroll
        for (int off = 32; off > 0; off >>= 1) v += __shfl_down(v, off, 64);
        if ((t & 63) == 0) sred[t >> 6][b] = v;
    }
    __syncthreads();
    if (t < 8) {
        const float S = sred[0][t] + sred[1][t] + sred[2][t] + sred[3][t];
        siginv[t * COUT + o] = rsqrtf(S * (1.0f / (float)KTOT) + 1e-8f);
    }
}

// ---------------- Phase 2: implicit-GEMM conv ----------------
// block: 128 o x (4 rows x 64 cols). 4 waves: (oh = wid&1, rp = wid>>1),
// each wave 64 o x 128 px -> acc[4][8].
// Weights are batch-independent (4.72 MB total; 1.18 MB per XCD -> L2-hot).
__global__ __launch_bounds__(256, 2) void conv_kernel(const unsigned short* __restrict__ wpk,
                                                      const unsigned short* __restrict__ xtp,
                                                      const float* __restrict__ siginv,
                                                      const float* __restrict__ bias,
                                                      float* __restrict__ out) {
    __shared__ __align__(16) unsigned short xs[6 * NSL * 64];   // 50688 B
    // XCD-aware decode: XCD k = bid&7 owns ob = k&3 (1.18 MB weight quarter) and
    // batches (k>>2)*4 .. +3.
    const int bid = blockIdx.x;
    const int k  = bid & 7;
    const int q  = bid >> 3;            // 0..63
    const int ob = k & 3;
    const int b  = (k >> 2) * 4 + (q >> 4);
    const int yb = q & 15;

    const int tid  = threadIdx.x;
    const int lane = tid & 63, wid = tid >> 6;
    const int l15 = lane & 15, l4 = lane >> 4;
    const int l8  = lane & 7,  lq = lane >> 3;
    const int oh = wid & 1, rp = wid >> 1;
    const int y0 = yb * 4;
    const int g0 = ob * 8 + oh * 4;

    f32x4 acc[4][8];
#pragma unroll
    for (int mi = 0; mi < 4; ++mi)
#pragma unroll
        for (int j = 0; j < 8; ++j) acc[mi][j] = (f32x4){0.f, 0.f, 0.f, 0.f};

#define LOAD_AF(dst, tap, c)                                                              \
    do {                                                                                  \
        _Pragma("unroll") for (int mi = 0; mi < 4; ++mi)                                  \
            dst[mi] = *(const short8*)(wpk +                                              \
                ((((size_t)(tap) * 32 + g0 + mi) * 16 + (c)) * 64 + lane) * 8);           \
    } while (0)

#define COMPUTE(af, ky, kx, ks)                                                           \
    do {                                                                                  \
        short8 bfr[8];                                                                    \
        _Pragma("unroll") for (int j = 0; j < 8; ++j) {                                   \
            const int irow = rp * 2 + (j >> 2) + (ky);                                    \
            const int icol = (j & 3) * 16 + l15 + (kx);                                   \
            const int unit = ((ks) * 4 + l4) ^ ((l15 + (kx)) & 7);                        \
            bfr[j] = *(const short8*)(xs + (irow * NSL + icol) * 64 + unit * 8);          \
        }                                                                                 \
        _Pragma("unroll") for (int mi = 0; mi < 4; ++mi)                                  \
            _Pragma("unroll") for (int j = 0; j < 8; ++j)                                 \
                acc[mi][j] = __builtin_amdgcn_mfma_f32_16x16x32_bf16(                     \
                    af[mi], bfr[j], acc[mi][j], 0, 0, 0);                                 \
    } while (0)

    short8 afA[4], afB[4];
    LOAD_AF(afA, 0, 0);

#pragma unroll 1
    for (int ic = 0; ic < 8; ++ic) {
        __syncthreads();
        // stage 6 rows x 66 slices of 128B via global_load_lds (pre-swizzled source)
        for (int qq = wid; qq < 54; qq += 4) {
            const int ir  = qq / 9;
            const int sub = qq - ir * 9;
            const int yin = y0 - 1 + ir;                       // -1..64 -> padded idx +1
            const unsigned short* srow =
                xtp + (size_t)(b * XPD + yin + 1) * XPD * 512;
            if (sub < 8) {
                const int xcol = sub * 8 + lq;                  // x&7 == lq
                gll16(srow + (size_t)xcol * 512 + ic * 64 + (l8 ^ lq) * 8,
                      xs + (ir * NSL + sub * 8) * 64);
            } else if (lane < 16) {
                const int xcol = 64 + lq;                       // lq in {0,1}, x&7 == lq
                gll16(srow + (size_t)xcol * 512 + ic * 64 + (l8 ^ lq) * 8,
                      xs + (ir * NSL + 64) * 64);
            }
        }
        __syncthreads();

        const int c0 = ic * 2, c1 = c0 + 1;
        const int cn = (ic < 7) ? c0 + 2 : 0;
#pragma unroll
        for (int tp = 0; tp < 9; ++tp) {
            const int ky = tp / 3, kx = tp % 3;
            LOAD_AF(afB, tp, c1);
            COMPUTE(afA, ky, kx, 0);
            if (tp < 8) { LOAD_AF(afA, tp + 1, c0); }
            else        { LOAD_AF(afA, 0, cn); }
            COMPUTE(afB, ky, kx, 1);
        }
    }

    // epilogue: D-frag col = l15 (px), row = l4*4 + rr (o); scale by sigma_inv, add bias
#pragma unroll
    for (int mi = 0; mi < 4; ++mi) {
        const int obase = ob * 128 + oh * 64 + mi * 16 + l4 * 4;
#pragma unroll
        for (int rr = 0; rr < 4; ++rr) {
            const int o = obase + rr;
            const float sv = siginv[b * COUT + o];
            const float bv = bias[o];
#pragma unroll
            for (int j = 0; j < 8; ++j) {
                const int yout = y0 + rp * 2 + (j >> 2);
                out[(((size_t)(b * COUT + o) * HH + yout) << 6) + (j & 3) * 16 + l15] =
                    acc[mi][j][rr] * sv + bv;
            }
        }
    }
#undef LOAD_AF
#undef COMPUTE
}

extern "C" void kernel_launch(void* const* d_in, const int* in_sizes, int n_in,
                              void* d_out, int out_size, void* d_ws, size_t ws_size,
                              hipStream_t stream) {
    const float* x      = (const float*)d_in[0];
    const float* style  = (const float*)d_in[1];
    const float* weight = (const float*)d_in[2];
    const float* bias   = (const float*)d_in[3];
    float* out = (float*)d_out;

    unsigned short* wpk = (unsigned short*)d_ws;                  // 9*32*16*64*8 = 2359296 shorts (4.72 MB)
    unsigned short* xtp = wpk + (size_t)2359296;                  // 8*66*66*512 shorts (35.7 MB)
    float* siginv = (float*)(xtp + (size_t)BB * XPD * XPD * 512); // 8*512 f32

    zring_kernel<<<520, 256, 0, stream>>>(xtp);
    xpose_kernel<<<dim3(16, HH, BB), 256, 0, stream>>>(x, style, xtp);
    wpack_kernel<<<COUT, 256, 0, stream>>>(weight, wpk);
    sigma_kernel<<<COUT, 256, 0, stream>>>(weight, style, siginv);
    conv_kernel<<<512, 256, 0, stream>>>(wpk, xtp, siginv, bias, out);
}

// Round 4
// 219.623 us; speedup vs baseline: 1.7959x; 1.6748x over previous
//
#include <hip/hip_runtime.h>

#define CIN 512
#define COUT 512
#define HH 64
#define WW 64
#define BB 8
#define KTOT 4608   // 512*9

#define XPD 66      // padded spatial dim: index = coord+1, coord in -1..64
#define NSL 66      // LDS col-slices per row (icol 0..65)
#define BUFSH (6 * NSL * 64)   // shorts per LDS buffer (6 rows x 66 slices x 64 ch)

typedef __attribute__((ext_vector_type(8))) short short8;
typedef __attribute__((ext_vector_type(4))) float f32x4;

__device__ inline unsigned short f2bf(float f) {
    unsigned int u = __float_as_uint(f);
    u += 0x7FFFu + ((u >> 16) & 1u);   // round-to-nearest-even
    return (unsigned short)(u >> 16);
}

__device__ inline void gll16(const void* g, void* l) {
    __builtin_amdgcn_global_load_lds(
        (const __attribute__((address_space(1))) unsigned int*)g,
        (__attribute__((address_space(3))) unsigned int*)l, 16, 0, 0);
}

// ---------------- Phase -1: zero the halo ring of XTP ----------------
__global__ __launch_bounds__(256) void zring_kernel(unsigned short* __restrict__ xtp) {
    const int e = blockIdx.x * 256 + threadIdx.x;   // 520*256 >= 8*260*64
    if (e >= BB * 260 * 64) return;
    const int unit = e & 63;
    const int sa = e >> 6;           // 0..2079
    const int b = sa / 260;
    const int s = sa - b * 260;
    int yy, xx;
    if (s < 66)       { yy = 0;        xx = s; }
    else if (s < 132) { yy = 65;       xx = s - 66; }
    else if (s < 196) { yy = s - 131;  xx = 0; }     // rows 1..64
    else              { yy = s - 195;  xx = 65; }    // rows 1..64
    *(short8*)(xtp + ((size_t)(b * XPD + yy) * XPD + xx) * 512 + unit * 8) =
        (short8){0, 0, 0, 0, 0, 0, 0, 0};
}

// ------- Phase 0: x [b][i][y][x] fp32 * (1+style[b][i]) -> XTP [b][y+1][x+1][i] bf16 -------
__global__ __launch_bounds__(256) void xpose_kernel(const float* __restrict__ x,
                                                    const float* __restrict__ style,
                                                    unsigned short* __restrict__ xtp) {
    __shared__ float tile[32 * 65];
    __shared__ float sst[32];
    const int ic = blockIdx.x;   // 16 groups of 32 channels
    const int y  = blockIdx.y;
    const int b  = blockIdx.z;
    const int t  = threadIdx.x;
    if (t < 32) sst[t] = style[b * CIN + ic * 32 + t] + 1.0f;
#pragma unroll
    for (int it = 0; it < 8; ++it) {
        int e = it * 256 + t;
        int ii = e >> 6, xx = e & 63;
        tile[ii * 65 + xx] = x[(((size_t)(b * CIN + ic * 32 + ii) * HH + y) << 6) + xx];
    }
    __syncthreads();
#pragma unroll
    for (int it = 0; it < 8; ++it) {
        int g = it * 256 + t;
        int xx = g >> 5, ii = g & 31;
        xtp[((size_t)(b * XPD + y + 1) * XPD + xx + 1) * 512 + ic * 32 + ii] =
            f2bf(tile[ii * 65 + xx] * sst[ii]);
    }
}

// ---------------- Phase 1a: pack w*c into MFMA fragment layout (batch-independent) -------
// Wpk flat: (((tap*32 + g)*16 + c)*64 + lane)*8 + e ; lane = l4*16+l15 holds
//   W[o = g*16+l15][i = c*32 + l4*8 + e]
__global__ __launch_bounds__(256) void wpack_kernel(const float* __restrict__ weight,
                                                    unsigned short* __restrict__ wpk) {
    __shared__ float q[KTOT];
    const int o = blockIdx.x;
    const int t = threadIdx.x;
    const float* wrow = weight + (size_t)o * KTOT;   // e = i*9+tap
    const float cst = 1.0f / sqrtf((float)KTOT);
#pragma unroll
    for (int it = 0; it < 18; ++it) {
        int e = it * 256 + t;
        q[e] = wrow[e] * cst;
    }
    __syncthreads();
    const int g = o >> 4, l15 = o & 15;
    for (int m = t; m < 576; m += 256) {   // (tap, c, l4)
        int tap = m / 64;
        int rem = m & 63;
        int c   = rem >> 2;
        int l4  = rem & 3;
        short8 v;
#pragma unroll
        for (int e = 0; e < 8; ++e)
            v[e] = (short)f2bf(q[(c * 32 + l4 * 8 + e) * 9 + tap]);
        *(short8*)(wpk + ((((size_t)tap * 32 + g) * 16 + c) * 64 + l4 * 16 + l15) * 8) = v;
    }
}

// ---------------- Phase 1b: sigma_inv[b][o] = rsqrt(c^2 * sum_i wsq[o,i]*(1+s)^2 + eps) ----
__global__ __launch_bounds__(256) void sigma_kernel(const float* __restrict__ weight,
                                                    const float* __restrict__ style,
                                                    float* __restrict__ siginv) {
    __shared__ float sred[4][8];
    const int o = blockIdx.x;
    const int t = threadIdx.x;
    const float* wrow = weight + (size_t)o * KTOT;
    float acc[8] = {0.f, 0.f, 0.f, 0.f, 0.f, 0.f, 0.f, 0.f};
#pragma unroll
    for (int ii = 0; ii < 2; ++ii) {
        const int i = t * 2 + ii;
        float wsq = 0.f;
#pragma unroll
        for (int tap = 0; tap < 9; ++tap) {
            float v = wrow[i * 9 + tap];
            wsq += v * v;
        }
#pragma unroll
        for (int b = 0; b < 8; ++b) {
            float s = style[b * CIN + i] + 1.0f;
            acc[b] += wsq * s * s;
        }
    }
#pragma unroll
    for (int b = 0; b < 8; ++b) {
        float v = acc[b];
#pragma unroll
        for (int off = 32; off > 0; off >>= 1) v += __shfl_down(v, off, 64);
        if ((t & 63) == 0) sred[t >> 6][b] = v;
    }
    __syncthreads();
    if (t < 8) {
        const float S = sred[0][t] + sred[1][t] + sred[2][t] + sred[3][t];
        siginv[t * COUT + o] = rsqrtf(S * (1.0f / (float)KTOT) + 1e-8f);
    }
}

// ---------------- Phase 2: implicit-GEMM conv ----------------
// block: 512 thr = 8 waves; tile 256 o x 4 output rows x 64 cols.
// wave (og = wid&1, rp = wid>>2..): wave tile = 128 o x 1 row x 64 cols -> acc[8][4].
// X tile: 6 input rows x 66 slices x 64 ch, DOUBLE-BUFFERED (2x50.7KB), 1 block/CU.
// Per ic: {STAGE(next buf) ; compute(cur buf) ; barrier} -> staging hides under MFMA.
__global__ __launch_bounds__(512, 2) void conv_kernel(const unsigned short* __restrict__ wpk,
                                                      const unsigned short* __restrict__ xtp,
                                                      const float* __restrict__ siginv,
                                                      const float* __restrict__ bias,
                                                      float* __restrict__ out) {
    __shared__ __align__(16) unsigned short xs[2 * BUFSH];   // 101376 B
    // XCD-aware decode: XCD k = bid&7 owns ob = k&1 (2.36 MB weight half, L2-hot)
    // and batches (k>>1)*2 .. +1.
    const int bid = blockIdx.x;
    const int k  = bid & 7;
    const int tq = bid >> 3;            // 0..31
    const int ob = k & 1;
    const int b  = (k >> 1) * 2 + (tq >> 4);
    const int yb = tq & 15;

    const int tid  = threadIdx.x;
    const int lane = tid & 63, wid = tid >> 6;
    const int l15 = lane & 15, l4 = lane >> 4;
    const int l8  = lane & 7,  lq = lane >> 3;
    const int og = wid & 1, rp = wid >> 1;
    const int y0 = yb * 4;
    const int g0 = ob * 16 + og * 8;    // o-frag base (frags of 16)

    f32x4 acc[8][4];
#pragma unroll
    for (int mi = 0; mi < 8; ++mi)
#pragma unroll
        for (int j = 0; j < 4; ++j) acc[mi][j] = (f32x4){0.f, 0.f, 0.f, 0.f};

#define STAGE(bufp, icq)                                                                  \
    do {                                                                                  \
        for (int qq = wid; qq < 54; qq += 8) {                                            \
            const int ir  = qq / 9;                                                       \
            const int sub = qq - ir * 9;                                                  \
            const int yin = y0 - 1 + ir;                                                  \
            const unsigned short* srow = xtp + (size_t)(b * XPD + yin + 1) * XPD * 512;   \
            if (sub < 8) {                                                                \
                const int xcol = sub * 8 + lq;                                            \
                gll16(srow + (size_t)xcol * 512 + (icq) * 64 + (l8 ^ lq) * 8,             \
                      xs + (bufp) * BUFSH + (ir * NSL + sub * 8) * 64);                   \
            } else if (lane < 16) {                                                       \
                const int xcol = 64 + lq;                                                 \
                gll16(srow + (size_t)xcol * 512 + (icq) * 64 + (l8 ^ lq) * 8,             \
                      xs + (bufp) * BUFSH + (ir * NSL + 64) * 64);                        \
            }                                                                             \
        }                                                                                 \
    } while (0)

#define LOAD_A8(dst, tap, c)                                                              \
    do {                                                                                  \
        _Pragma("unroll") for (int mi = 0; mi < 8; ++mi)                                  \
            dst[mi] = *(const short8*)(wpk +                                              \
                ((((size_t)(tap) * 32 + g0 + mi) * 16 + (c)) * 64 + lane) * 8);           \
    } while (0)

#define COMPUTE(af, ky, kx, ks, base)                                                     \
    do {                                                                                  \
        short8 bfr[4];                                                                    \
        const int irow = rp + (ky);                                                       \
        _Pragma("unroll") for (int j = 0; j < 4; ++j) {                                   \
            const int icol = j * 16 + l15 + (kx);                                         \
            const int unit = ((ks) * 4 + l4) ^ ((l15 + (kx)) & 7);                        \
            bfr[j] = *(const short8*)(xs + (base) + (irow * NSL + icol) * 64 + unit * 8); \
        }                                                                                 \
        _Pragma("unroll") for (int mi = 0; mi < 8; ++mi)                                  \
            _Pragma("unroll") for (int j = 0; j < 4; ++j)                                 \
                acc[mi][j] = __builtin_amdgcn_mfma_f32_16x16x32_bf16(                     \
                    af[mi], bfr[j], acc[mi][j], 0, 0, 0);                                 \
    } while (0)

    STAGE(0, 0);
    __syncthreads();

    short8 afA[8], afB[8];
    LOAD_A8(afA, 0, 0);

#pragma unroll 1
    for (int ic = 0; ic < 8; ++ic) {
        if (ic < 7) STAGE((ic + 1) & 1, ic + 1);
        const int base = (ic & 1) * BUFSH;
        const int c0 = ic * 2, c1 = c0 + 1;
        const int cn = (ic < 7) ? c0 + 2 : 0;
#pragma unroll
        for (int tp = 0; tp < 9; ++tp) {
            const int ky = tp / 3, kx = tp % 3;
            LOAD_A8(afB, tp, c1);
            COMPUTE(afA, ky, kx, 0, base);
            if (tp < 8) { LOAD_A8(afA, tp + 1, c0); }
            else        { LOAD_A8(afA, 0, cn); }
            COMPUTE(afB, ky, kx, 1, base);
        }
        __syncthreads();   // implicit vmcnt(0) drain lands ~full compute after STAGE issue
    }

    // epilogue: D-frag col = l15 (px), row = l4*4 + rr (o); scale by sigma_inv, add bias
    const int yout = y0 + rp;
#pragma unroll
    for (int mi = 0; mi < 8; ++mi) {
        const int obase = ob * 256 + og * 128 + mi * 16 + l4 * 4;
#pragma unroll
        for (int rr = 0; rr < 4; ++rr) {
            const int o = obase + rr;
            const float sv = siginv[b * COUT + o];
            const float bv = bias[o];
            float* orow = out + (((size_t)(b * COUT + o) * HH + yout) << 6);
#pragma unroll
            for (int j = 0; j < 4; ++j) {
                orow[j * 16 + l15] = acc[mi][j][rr] * sv + bv;
            }
        }
    }
#undef STAGE
#undef LOAD_A8
#undef COMPUTE
}

extern "C" void kernel_launch(void* const* d_in, const int* in_sizes, int n_in,
                              void* d_out, int out_size, void* d_ws, size_t ws_size,
                              hipStream_t stream) {
    const float* x      = (const float*)d_in[0];
    const float* style  = (const float*)d_in[1];
    const float* weight = (const float*)d_in[2];
    const float* bias   = (const float*)d_in[3];
    float* out = (float*)d_out;

    unsigned short* wpk = (unsigned short*)d_ws;                  // 9*32*16*64*8 shorts (4.72 MB)
    unsigned short* xtp = wpk + (size_t)2359296;                  // 8*66*66*512 shorts (35.7 MB)
    float* siginv = (float*)(xtp + (size_t)BB * XPD * XPD * 512); // 8*512 f32

    zring_kernel<<<520, 256, 0, stream>>>(xtp);
    xpose_kernel<<<dim3(16, HH, BB), 256, 0, stream>>>(x, style, xtp);
    wpack_kernel<<<COUT, 256, 0, stream>>>(weight, wpk);
    sigma_kernel<<<COUT, 256, 0, stream>>>(weight, style, siginv);
    conv_kernel<<<256, 512, 0, stream>>>(wpk, xtp, siginv, bias, out);
}

// Round 5
// 166.127 us; speedup vs baseline: 2.3742x; 1.3220x over previous
//
#include <hip/hip_runtime.h>

#define CIN 512
#define COUT 512
#define HH 64
#define WW 64
#define BB 8
#define KTOT 4608   // 512*9

#define XPD 66      // padded spatial dim: index = coord+1, coord in -1..64
#define NSL 66      // LDS col-slices per row (icol 0..65)
#define BUFSH (6 * NSL * 64)   // shorts per LDS buffer (6 rows x 66 slices x 64 ch)

typedef __attribute__((ext_vector_type(8))) short short8;
typedef __attribute__((ext_vector_type(4))) float f32x4;

__device__ inline unsigned short f2bf(float f) {
    unsigned int u = __float_as_uint(f);
    u += 0x7FFFu + ((u >> 16) & 1u);   // round-to-nearest-even
    return (unsigned short)(u >> 16);
}

__device__ inline void gll16(const void* g, void* l) {
    __builtin_amdgcn_global_load_lds(
        (const __attribute__((address_space(1))) unsigned int*)g,
        (__attribute__((address_space(3))) unsigned int*)l, 16, 0, 0);
}

// ---------------- Phase -1: zero the halo ring of XTP ----------------
__global__ __launch_bounds__(256) void zring_kernel(unsigned short* __restrict__ xtp) {
    const int e = blockIdx.x * 256 + threadIdx.x;   // 520*256 >= 8*260*64
    if (e >= BB * 260 * 64) return;
    const int unit = e & 63;
    const int sa = e >> 6;           // 0..2079
    const int b = sa / 260;
    const int s = sa - b * 260;
    int yy, xx;
    if (s < 66)       { yy = 0;        xx = s; }
    else if (s < 132) { yy = 65;       xx = s - 66; }
    else if (s < 196) { yy = s - 131;  xx = 0; }     // rows 1..64
    else              { yy = s - 195;  xx = 65; }    // rows 1..64
    *(short8*)(xtp + ((size_t)(b * XPD + yy) * XPD + xx) * 512 + unit * 8) =
        (short8){0, 0, 0, 0, 0, 0, 0, 0};
}

// ------- Phase 0: x [b][i][y][x] fp32 * (1+style[b][i]) -> XTP [b][y+1][x+1][i] bf16 -------
__global__ __launch_bounds__(256) void xpose_kernel(const float* __restrict__ x,
                                                    const float* __restrict__ style,
                                                    unsigned short* __restrict__ xtp) {
    __shared__ float tile[32 * 65];
    __shared__ float sst[32];
    const int ic = blockIdx.x;   // 16 groups of 32 channels
    const int y  = blockIdx.y;
    const int b  = blockIdx.z;
    const int t  = threadIdx.x;
    if (t < 32) sst[t] = style[b * CIN + ic * 32 + t] + 1.0f;
#pragma unroll
    for (int it = 0; it < 8; ++it) {
        int e = it * 256 + t;
        int ii = e >> 6, xx = e & 63;
        tile[ii * 65 + xx] = x[(((size_t)(b * CIN + ic * 32 + ii) * HH + y) << 6) + xx];
    }
    __syncthreads();
#pragma unroll
    for (int it = 0; it < 8; ++it) {
        int g = it * 256 + t;
        int xx = g >> 5, ii = g & 31;
        xtp[((size_t)(b * XPD + y + 1) * XPD + xx + 1) * 512 + ic * 32 + ii] =
            f2bf(tile[ii * 65 + xx] * sst[ii]);
    }
}

// ---------------- Phase 1a: pack w*c into MFMA fragment layout (batch-independent) -------
// Wpk flat: (((c*9 + tap)*32 + g)*64 + lane)*8 + e ; lane = l4*16+l15 holds
//   W[o = g*16+l15][i = c*32 + l4*8 + e],  c = 16 chunks of 32 input ch.
// [c][tap][g] order => conv's per-(c,tap) 8-frag A-load is one SGPR base + imm offsets.
__global__ __launch_bounds__(256) void wpack_kernel(const float* __restrict__ weight,
                                                    unsigned short* __restrict__ wpk) {
    __shared__ float q[KTOT];
    const int o = blockIdx.x;
    const int t = threadIdx.x;
    const float* wrow = weight + (size_t)o * KTOT;   // e = i*9+tap
    const float cst = 1.0f / sqrtf((float)KTOT);
#pragma unroll
    for (int it = 0; it < 18; ++it) {
        int e = it * 256 + t;
        q[e] = wrow[e] * cst;
    }
    __syncthreads();
    const int g = o >> 4, l15 = o & 15;
    for (int m = t; m < 576; m += 256) {   // m -> (c, tap, l4)
        int c   = m / 36;
        int rem = m - c * 36;
        int tap = rem >> 2;
        int l4  = rem & 3;
        short8 v;
#pragma unroll
        for (int e = 0; e < 8; ++e)
            v[e] = (short)f2bf(q[(c * 32 + l4 * 8 + e) * 9 + tap]);
        *(short8*)(wpk + ((((size_t)c * 9 + tap) * 32 + g) * 64 + l4 * 16 + l15) * 8) = v;
    }
}

// ---------------- Phase 1b: sigma_inv[b][o] = rsqrt(c^2 * sum_i wsq[o,i]*(1+s)^2 + eps) ----
__global__ __launch_bounds__(256) void sigma_kernel(const float* __restrict__ weight,
                                                    const float* __restrict__ style,
                                                    float* __restrict__ siginv) {
    __shared__ float sred[4][8];
    const int o = blockIdx.x;
    const int t = threadIdx.x;
    const float* wrow = weight + (size_t)o * KTOT;
    float acc[8] = {0.f, 0.f, 0.f, 0.f, 0.f, 0.f, 0.f, 0.f};
#pragma unroll
    for (int ii = 0; ii < 2; ++ii) {
        const int i = t * 2 + ii;
        float wsq = 0.f;
#pragma unroll
        for (int tap = 0; tap < 9; ++tap) {
            float v = wrow[i * 9 + tap];
            wsq += v * v;
        }
#pragma unroll
        for (int b = 0; b < 8; ++b) {
            float s = style[b * CIN + i] + 1.0f;
            acc[b] += wsq * s * s;
        }
    }
#pragma unroll
    for (int b = 0; b < 8; ++b) {
        float v = acc[b];
#pragma unroll
        for (int off = 32; off > 0; off >>= 1) v += __shfl_down(v, off, 64);
        if ((t & 63) == 0) sred[t >> 6][b] = v;
    }
    __syncthreads();
    if (t < 8) {
        const float S = sred[0][t] + sred[1][t] + sred[2][t] + sred[3][t];
        siginv[t * COUT + o] = rsqrtf(S * (1.0f / (float)KTOT) + 1e-8f);
    }
}

// ---------------- Phase 2: implicit-GEMM conv ----------------
// block: 512 thr = 8 waves; tile 256 o x 4 output rows x 64 cols.
// wave (og, rp) [scalar via readfirstlane]: 128 o x 1 row x 64 px -> acc[8][4].
// X: 6 rows x 66 slices x 64 ch, double-buffered; A: 2-deep static prefetch rotation.
__global__ __launch_bounds__(512, 2) void conv_kernel(const unsigned short* __restrict__ wpk,
                                                      const unsigned short* __restrict__ xtp,
                                                      const float* __restrict__ siginv,
                                                      const float* __restrict__ bias,
                                                      float* __restrict__ out) {
    __shared__ __align__(16) unsigned short xs[2 * BUFSH];   // 101376 B
    // XCD-aware decode: XCD k = bid&7 owns ob = k&1 (2.36 MB weight half, L2-hot)
    const int bid = blockIdx.x;
    const int k  = bid & 7;
    const int tq = bid >> 3;            // 0..31
    const int ob = k & 1;
    const int b  = (k >> 1) * 2 + (tq >> 4);
    const int yb = tq & 15;

    const int tid  = threadIdx.x;
    const int lane = tid & 63;
    const int wid_u = __builtin_amdgcn_readfirstlane(tid >> 6);   // wave-uniform -> SGPR
    const int l15 = lane & 15, l4 = lane >> 4;
    const int l8  = lane & 7,  lq = lane >> 3;
    const int og = wid_u & 1, rp = wid_u >> 1;
    const int y0 = yb * 4;
    const int g0 = ob * 16 + og * 8;    // o-frag base (frags of 16), scalar

    // precomputed swizzled B ds byte-voffsets, static-indexed in the unrolled loop
    int vB[3][2];
#pragma unroll
    for (int kx = 0; kx < 3; ++kx)
#pragma unroll
        for (int ks = 0; ks < 2; ++ks)
            vB[kx][ks] = (l15 + kx) * 128 + (((ks * 4 + l4) ^ ((l15 + kx) & 7)) * 16);

    f32x4 acc[8][4];
#pragma unroll
    for (int mi = 0; mi < 8; ++mi)
#pragma unroll
        for (int j = 0; j < 4; ++j) acc[mi][j] = (f32x4){0.f, 0.f, 0.f, 0.f};

    short8 af[3][8];   // 2-deep prefetch rotation, static indices only

#define STAGE(bufp, icq)                                                                  \
    do {                                                                                  \
        for (int qq = wid_u; qq < 54; qq += 8) {                                          \
            const int ir  = qq / 9;                                                       \
            const int sub = qq - ir * 9;                                                  \
            const int yin = y0 - 1 + ir;                                                  \
            const unsigned short* srow = xtp + (size_t)(b * XPD + yin + 1) * XPD * 512;   \
            if (sub < 8) {                                                                \
                const int xcol = sub * 8 + lq;                                            \
                gll16(srow + (size_t)xcol * 512 + (icq) * 64 + (l8 ^ lq) * 8,             \
                      xs + (bufp) * BUFSH + (ir * NSL + sub * 8) * 64);                   \
            } else if (lane < 16) {                                                       \
                const int xcol = 64 + lq;                                                 \
                gll16(srow + (size_t)xcol * 512 + (icq) * 64 + (l8 ^ lq) * 8,             \
                      xs + (bufp) * BUFSH + (ir * NSL + 64) * 64);                        \
            }                                                                             \
        }                                                                                 \
    } while (0)

    // A-set s (per ic): tap = s>>1, ks = s&1, c = ic*2+ks; 8 frags from one scalar base
#define LOAD_SET(slot, icv, s)                                                            \
    do {                                                                                  \
        const unsigned short* ab = wpk +                                                  \
            ((size_t)(((icv) * 2 + ((s) & 1)) * 9 + ((s) >> 1)) * 32 + g0) * 512;         \
        _Pragma("unroll") for (int mi = 0; mi < 8; ++mi)                                  \
            af[slot][mi] = *(const short8*)(ab + mi * 512 + lane * 8);                    \
    } while (0)

#define COMPUTE(slot, ky, kx, ks, cbase)                                                  \
    do {                                                                                  \
        short8 bfr[4];                                                                    \
        const char* bp = (const char*)xs + (cbase) + (rp + (ky)) * (NSL * 128) +          \
                         vB[kx][ks];                                                      \
        _Pragma("unroll") for (int j = 0; j < 4; ++j)                                     \
            bfr[j] = *(const short8*)(bp + j * 2048);                                     \
        __builtin_amdgcn_s_setprio(1);                                                    \
        _Pragma("unroll") for (int mi = 0; mi < 8; ++mi)                                  \
            _Pragma("unroll") for (int j = 0; j < 4; ++j)                                 \
                acc[mi][j] = __builtin_amdgcn_mfma_f32_16x16x32_bf16(                     \
                    af[slot][mi], bfr[j], acc[mi][j], 0, 0, 0);                           \
        __builtin_amdgcn_s_setprio(0);                                                    \
    } while (0)

    STAGE(0, 0);
    LOAD_SET(0, 0, 0);
    LOAD_SET(1, 0, 1);
    __syncthreads();

#pragma unroll 1
    for (int ic = 0; ic < 8; ++ic) {
        if (ic < 7) STAGE((ic + 1) & 1, ic + 1);
        const int cbase = (ic & 1) * (BUFSH * 2);   // bytes
#pragma unroll
        for (int s = 0; s < 18; ++s) {
            if (s < 16) { LOAD_SET((s + 2) % 3, ic, s + 2); }
            else        { LOAD_SET((s + 2) % 3, ic + 1, s - 16); }  // ic=7 wraps into ws: harmless
            COMPUTE(s % 3, (s >> 1) / 3, (s >> 1) % 3, s & 1, cbase);
        }
        __syncthreads();
    }

    // epilogue: D-frag col = l15 (px), row = l4*4 + rr (o); scale by sigma_inv, add bias
    const int yout = y0 + rp;
#pragma unroll
    for (int mi = 0; mi < 8; ++mi) {
        const int obase = ob * 256 + og * 128 + mi * 16 + l4 * 4;
#pragma unroll
        for (int rr = 0; rr < 4; ++rr) {
            const int o = obase + rr;
            const float sv = siginv[b * COUT + o];
            const float bv = bias[o];
            float* orow = out + (((size_t)(b * COUT + o) * HH + yout) << 6);
#pragma unroll
            for (int j = 0; j < 4; ++j) {
                orow[j * 16 + l15] = acc[mi][j][rr] * sv + bv;
            }
        }
    }
#undef STAGE
#undef LOAD_SET
#undef COMPUTE
}

extern "C" void kernel_launch(void* const* d_in, const int* in_sizes, int n_in,
                              void* d_out, int out_size, void* d_ws, size_t ws_size,
                              hipStream_t stream) {
    const float* x      = (const float*)d_in[0];
    const float* style  = (const float*)d_in[1];
    const float* weight = (const float*)d_in[2];
    const float* bias   = (const float*)d_in[3];
    float* out = (float*)d_out;

    unsigned short* wpk = (unsigned short*)d_ws;                  // 16*9*32*64*8 shorts (4.72 MB)
    unsigned short* xtp = wpk + (size_t)2359296;                  // 8*66*66*512 shorts (35.7 MB)
    float* siginv = (float*)(xtp + (size_t)BB * XPD * XPD * 512); // 8*512 f32

    zring_kernel<<<520, 256, 0, stream>>>(xtp);
    xpose_kernel<<<dim3(16, HH, BB), 256, 0, stream>>>(x, style, xtp);
    wpack_kernel<<<COUT, 256, 0, stream>>>(weight, wpk);
    sigma_kernel<<<COUT, 256, 0, stream>>>(weight, style, siginv);
    conv_kernel<<<256, 512, 0, stream>>>(wpk, xtp, siginv, bias, out);
}